// Round 4
// baseline (739.855 us; speedup 1.0000x reference)
//
#include <hip/hip_runtime.h>
#include <math.h>

// global_powermean_pooling, P = 2.0
//   out[g, d] = sqrt( mean_{n : batch[n]==g} x[n, d]^2 ),  empty segment -> 0
// x: [N, 128] fp32, batch: [N] int32 sorted ascending in [0, G)
//
// R5 — INSTRUMENTED ROUND (double-pass pool; pass 2 removed next round).
// Why: three structurally different pool kernels (R1 streams / R2 split+NT /
// R4 sweep) all land at ~306us for a 512MB cold read (~1.7 TB/s), while the
// harness fill writes 2GB at 6.3 TB/s and R3's ProbeA read the same data at
// ~3 TB/s HBM once the LLC was clean/warm. Surviving theory: the 2GB ws
// poison fill leaves the 256MB LLC full of DIRTY lines; our cold read pays
// ~256MB of interleaved writebacks (read/write turnaround) -> ~1.7 TB/s.
// The pool kernel has never surfaced in top-5 (hides under the 320us fills),
// so this round doubles the pool's work (pass 1 forward + pass 2 backward,
// sums doubled, finalize halves) to push it to ~450us = top-1 dispatch with
// full counters. Decisive read: pool WRITE_SIZE ~2.6e5 KB => writeback theory
// confirmed; ~2e3 KB => refuted, read micro-structure is the problem
// (then check OccupancyPercent / VALUBusy on the same row).

#define D_FEAT 128
#define DV 32            // float4 per row
#define SWEEP_GRID 2048  // 8 blocks/CU
#define CHUNK 64         // rows per sweep chunk (32 KB)

typedef float f32x4 __attribute__((ext_vector_type(4)));

// ---- Kernel A: segment offsets ------------------------------------------
__global__ __launch_bounds__(256) void seg_offsets_kernel(
    const int* __restrict__ batch, int* __restrict__ off, int N, int G)
{
    int i = blockIdx.x * blockDim.x + threadIdx.x;
    if (i >= N) return;
    int cur = batch[i];
    if (i == 0) {
        for (int g = 0; g <= cur; ++g) off[g] = 0;
    } else {
        int prev = batch[i - 1];
        for (int g = prev + 1; g <= cur; ++g) off[g] = i;
    }
    if (i == N - 1) {
        for (int g = cur + 1; g <= G; ++g) off[g] = N;
    }
}

// ---- Kernel Z: zero the output accumulator ------------------------------
__global__ __launch_bounds__(256) void zero_out_kernel(f32x4* __restrict__ out4, int n4)
{
    int i = blockIdx.x * 256 + threadIdx.x;
    if (i < n4) out4[i] = (f32x4)0.f;
}

// ---- per-chunk worker (uniform control flow; called by both passes) ------
__device__ __forceinline__ void pool_chunk(
    const f32x4* __restrict__ x4,
    const int*   __restrict__ batch,
    const int*   __restrict__ off,
    float*       __restrict__ out,
    f32x4* red, int rs, int re, int tid, int fg, int lane)
{
    int cur = rs;
    int g = batch[rs];                 // block-uniform
    while (cur < re) {
        const int ge = off[g + 1];
        const int run_end = (ge < re) ? ge : re;

        f32x4 a0 = (f32x4)0.f, a1 = (f32x4)0.f, a2 = (f32x4)0.f, a3 = (f32x4)0.f;
        int r = cur + lane;
        for (; r + 24 < run_end; r += 32) {
            f32x4 v0 = x4[(size_t)(r     ) * DV + fg];
            f32x4 v1 = x4[(size_t)(r +  8) * DV + fg];
            f32x4 v2 = x4[(size_t)(r + 16) * DV + fg];
            f32x4 v3 = x4[(size_t)(r + 24) * DV + fg];
            a0 += v0 * v0; a1 += v1 * v1; a2 += v2 * v2; a3 += v3 * v3;
        }
        for (; r < run_end; r += 8) {
            f32x4 v = x4[(size_t)r * DV + fg];
            a0 += v * v;
        }
        a0 += a1; a2 += a3; a0 += a2;

        red[tid] = a0;
        __syncthreads();
        if (lane < 4) red[tid] += red[tid + 128];
        __syncthreads();
        if (lane < 2) red[tid] += red[tid + 64];
        __syncthreads();
        if (lane == 0) {
            f32x4 s = red[tid] + red[tid + 32];
            float* dst = out + (size_t)g * D_FEAT + fg * 4;
            atomicAdd(dst + 0, s[0]);
            atomicAdd(dst + 1, s[1]);
            atomicAdd(dst + 2, s[2]);
            atomicAdd(dst + 3, s[3]);
        }
        __syncthreads();               // red reused next run
        cur = run_end;
        if (cur < re) g = batch[cur];  // uniform
    }
}

// ---- Kernel S2: double-pass sweep pool (instrumented) -------------------
// Pass 1: forward sweep (cold LLC full of dirty ws lines -> measures the
// writeback tax). Pass 2: BACKWARD sweep (tail of x is LLC-resident after
// pass 1; reverse order maximizes hits under LRU-sweep). Every row is summed
// exactly twice; finalize divides by 2*count.
__global__ __launch_bounds__(256) void global_powermean_pooling_44126493999223_kernel(
    const f32x4* __restrict__ x4,
    const int*   __restrict__ batch,
    const int*   __restrict__ off,
    float*       __restrict__ out,
    int N)
{
    const int tid  = threadIdx.x;
    const int fg   = tid & 31;
    const int lane = tid >> 5;

    __shared__ f32x4 red[256];

    const int nchunks = (N + CHUNK - 1) / CHUNK;

    // pass 1: forward
    for (int c = blockIdx.x; c < nchunks; c += SWEEP_GRID) {
        const int rs = c * CHUNK;
        const int re = (rs + CHUNK < N) ? rs + CHUNK : N;
        pool_chunk(x4, batch, off, out, red, rs, re, tid, fg, lane);
    }
    // pass 2: backward (instrumentation; removed next round)
    const int kmax = (nchunks - 1 - blockIdx.x) / SWEEP_GRID;
    for (int c = blockIdx.x + kmax * SWEEP_GRID; c >= 0; c -= SWEEP_GRID) {
        const int rs = c * CHUNK;
        const int re = (rs + CHUNK < N) ? rs + CHUNK : N;
        pool_chunk(x4, batch, off, out, red, rs, re, tid, fg, lane);
    }
}

// ---- Kernel F: finalize sqrt(sum / (2*count)) ---------------------------
__global__ __launch_bounds__(128) void finalize_kernel(
    const int* __restrict__ off, float* __restrict__ out)
{
    const int g = blockIdx.x;
    const int d = threadIdx.x;
    const int cnt = off[g + 1] - off[g];
    const size_t i = (size_t)g * D_FEAT + d;
    const float v = out[i];
    // 0.5f: every row was accumulated twice (double-pass instrumentation)
    out[i] = (cnt > 0) ? sqrtf(v * (0.5f / (float)cnt)) : 0.f;
}

extern "C" void kernel_launch(void* const* d_in, const int* in_sizes, int n_in,
                              void* d_out, int out_size, void* d_ws, size_t ws_size,
                              hipStream_t stream) {
    const float* x     = (const float*)d_in[0];
    const int*   batch = (const int*)d_in[1];
    float*       out   = (float*)d_out;

    const int N = in_sizes[1];           // 1,000,000 nodes
    const int G = out_size / D_FEAT;     // 4096 graphs

    int* off = (int*)d_ws;               // (G+1) ints

    const int n4 = G * DV;

    seg_offsets_kernel<<<(N + 255) / 256, 256, 0, stream>>>(batch, off, N, G);
    zero_out_kernel<<<(n4 + 255) / 256, 256, 0, stream>>>((f32x4*)out, n4);
    global_powermean_pooling_44126493999223_kernel
        <<<SWEEP_GRID, 256, 0, stream>>>((const f32x4*)x, batch, off, out, N);
    finalize_kernel<<<G, 128, 0, stream>>>(off, out);
}

// Round 5
// 637.294 us; speedup vs baseline: 1.1609x; 1.1609x over previous
//
#include <hip/hip_runtime.h>
#include <math.h>

// global_powermean_pooling, P = 2.0
//   out[g, d] = sqrt( mean_{n : batch[n]==g} x[n, d]^2 ),  empty segment -> 0
// x: [N, 128] fp32, batch: [N] int32 sorted ascending in [0, G)
//
// R6 — sweep + NON-ALLOCATING reads (inline-asm global_load_dwordx4 sc0 sc1 nt).
// Evidence ledger:
//   * 2GB ws poison fill (~320us @ 6.4TB/s) is unconditional, inside the timed
//     window, and leaves the 256MB LLC full of DIRTY ws lines.
//   * R5 double-pass A/B: pass 2 (warm/clean) cost only +80.5us for 512MB —
//     the kernel structure is fine; timed pass 1 (~320us) pays a dirty-LLC
//     allocation/writeback tax. rocprof replay can't see it (clean replay
//     state: pool hides below the 313us fills every round).
//   * Fix attempt: reads that do NOT allocate in L2/LLC -> dirty lines stay
//     resident, their writeback falls outside our window, read is a pure HBM
//     stream. __builtin_nontemporal_load (nt only) was null in R2; this uses
//     the maximal combo sc0|sc1|nt (system-scope non-temporal) via inline asm.
// Structure: off-table scatter -> zero out -> sweep pool (asm NT loads,
// 4-deep batches per vmcnt wait) -> finalize sqrt(sum/count).

#define D_FEAT 128
#define DV 32            // float4 per row
#define SWEEP_GRID 2048  // 8 blocks/CU
#define CHUNK 64         // rows per sweep chunk (32 KB)

typedef float f32x4 __attribute__((ext_vector_type(4)));

// ---- non-allocating 16B load helpers ------------------------------------
// sc0 sc1 nt = system-scope non-temporal: no L0/L2 allocation, MALL no-alloc
// hint. Data dependency on the asm outputs orders the consumers; vmcnt(0)
// inside the asm makes the result architecturally ready (rule #18 safe: all
// consumers read asm outputs).
__device__ __forceinline__ void nt_load4x(
    const f32x4* p0, const f32x4* p1, const f32x4* p2, const f32x4* p3,
    f32x4& v0, f32x4& v1, f32x4& v2, f32x4& v3)
{
    asm volatile(
        "global_load_dwordx4 %0, %4, off sc0 sc1 nt\n\t"
        "global_load_dwordx4 %1, %5, off sc0 sc1 nt\n\t"
        "global_load_dwordx4 %2, %6, off sc0 sc1 nt\n\t"
        "global_load_dwordx4 %3, %7, off sc0 sc1 nt\n\t"
        "s_waitcnt vmcnt(0)"
        : "=&v"(v0), "=&v"(v1), "=&v"(v2), "=&v"(v3)
        : "v"(p0), "v"(p1), "v"(p2), "v"(p3));
}

__device__ __forceinline__ f32x4 nt_load1(const f32x4* p)
{
    f32x4 v;
    asm volatile(
        "global_load_dwordx4 %0, %1, off sc0 sc1 nt\n\t"
        "s_waitcnt vmcnt(0)"
        : "=&v"(v) : "v"(p));
    return v;
}

// ---- Kernel A: segment offsets ------------------------------------------
__global__ __launch_bounds__(256) void seg_offsets_kernel(
    const int* __restrict__ batch, int* __restrict__ off, int N, int G)
{
    int i = blockIdx.x * blockDim.x + threadIdx.x;
    if (i >= N) return;
    int cur = batch[i];
    if (i == 0) {
        for (int g = 0; g <= cur; ++g) off[g] = 0;
    } else {
        int prev = batch[i - 1];
        for (int g = prev + 1; g <= cur; ++g) off[g] = i;
    }
    if (i == N - 1) {
        for (int g = cur + 1; g <= G; ++g) off[g] = N;
    }
}

// ---- Kernel Z: zero the output accumulator ------------------------------
__global__ __launch_bounds__(256) void zero_out_kernel(f32x4* __restrict__ out4, int n4)
{
    int i = blockIdx.x * 256 + threadIdx.x;
    if (i < n4) out4[i] = (f32x4)0.f;
}

// ---- Kernel S: coordinated-sweep power-sum, non-allocating reads --------
__global__ __launch_bounds__(256) void global_powermean_pooling_44126493999223_kernel(
    const f32x4* __restrict__ x4,
    const int*   __restrict__ batch,
    const int*   __restrict__ off,
    float*       __restrict__ out,
    int N)
{
    const int tid  = threadIdx.x;
    const int fg   = tid & 31;   // float4 index within 128-wide row
    const int lane = tid >> 5;   // node-lane 0..7

    __shared__ f32x4 red[256];

    const int nchunks = (N + CHUNK - 1) / CHUNK;
    for (int c = blockIdx.x; c < nchunks; c += SWEEP_GRID) {
        const int rs = c * CHUNK;
        const int re = (rs + CHUNK < N) ? rs + CHUNK : N;
        int cur = rs;
        int g = batch[rs];                 // block-uniform broadcast load
        while (cur < re) {
            const int ge = off[g + 1];
            const int run_end = (ge < re) ? ge : re;

            f32x4 a0 = (f32x4)0.f, a1 = (f32x4)0.f, a2 = (f32x4)0.f, a3 = (f32x4)0.f;
            int r = cur + lane;
            for (; r + 24 < run_end; r += 32) {
                const f32x4* p0 = x4 + (size_t)(r     ) * DV + fg;
                const f32x4* p1 = x4 + (size_t)(r +  8) * DV + fg;
                const f32x4* p2 = x4 + (size_t)(r + 16) * DV + fg;
                const f32x4* p3 = x4 + (size_t)(r + 24) * DV + fg;
                f32x4 v0, v1, v2, v3;
                nt_load4x(p0, p1, p2, p3, v0, v1, v2, v3);
                a0 += v0 * v0; a1 += v1 * v1; a2 += v2 * v2; a3 += v3 * v3;
            }
            for (; r < run_end; r += 8) {
                f32x4 v = nt_load1(x4 + (size_t)r * DV + fg);
                a0 += v * v;
            }
            a0 += a1; a2 += a3; a0 += a2;

            red[tid] = a0;
            __syncthreads();
            if (lane < 4) red[tid] += red[tid + 128];
            __syncthreads();
            if (lane < 2) red[tid] += red[tid + 64];
            __syncthreads();
            if (lane == 0) {
                f32x4 s = red[tid] + red[tid + 32];
                float* dst = out + (size_t)g * D_FEAT + fg * 4;
                atomicAdd(dst + 0, s[0]);
                atomicAdd(dst + 1, s[1]);
                atomicAdd(dst + 2, s[2]);
                atomicAdd(dst + 3, s[3]);
            }
            __syncthreads();               // red reused next run
            cur = run_end;
            if (cur < re) g = batch[cur];  // uniform
        }
    }
}

// ---- Kernel F: finalize sqrt(sum / count) -------------------------------
__global__ __launch_bounds__(128) void finalize_kernel(
    const int* __restrict__ off, float* __restrict__ out)
{
    const int g = blockIdx.x;
    const int d = threadIdx.x;
    const int cnt = off[g + 1] - off[g];
    const size_t i = (size_t)g * D_FEAT + d;
    const float v = out[i];
    out[i] = (cnt > 0) ? sqrtf(v / (float)cnt) : 0.f;
}

extern "C" void kernel_launch(void* const* d_in, const int* in_sizes, int n_in,
                              void* d_out, int out_size, void* d_ws, size_t ws_size,
                              hipStream_t stream) {
    const float* x     = (const float*)d_in[0];
    const int*   batch = (const int*)d_in[1];
    float*       out   = (float*)d_out;

    const int N = in_sizes[1];           // 1,000,000 nodes
    const int G = out_size / D_FEAT;     // 4096 graphs

    int* off = (int*)d_ws;               // (G+1) ints

    const int n4 = G * DV;

    seg_offsets_kernel<<<(N + 255) / 256, 256, 0, stream>>>(batch, off, N, G);
    zero_out_kernel<<<(n4 + 255) / 256, 256, 0, stream>>>((f32x4*)out, n4);
    global_powermean_pooling_44126493999223_kernel
        <<<SWEEP_GRID, 256, 0, stream>>>((const f32x4*)x, batch, off, out, N);
    finalize_kernel<<<G, 128, 0, stream>>>(off, out);
}